// Round 1
// baseline (11082.627 us; speedup 1.0000x reference)
//
#include <hip/hip_runtime.h>
#include <stdint.h>

// UR-LSTM: B=128, T=512, I=512, H=512, OUT=256, 4H=2048
// Strategy: persistent 256-WG kernel; 4 row-groups x 64 col-slices.
// Per step: gates = [h|x_t](bf16 hi/lo split) @ [W_hh|W_ih]^T via 3-pass
// mfma_f32_32x32x16_bf16; per-row-group atomic barrier; c in registers.

#define NB 128
#define NT 512
#define NI 512
#define NH 512
#define NO 256

typedef short bf16x8 __attribute__((ext_vector_type(8)));
typedef float f32x16 __attribute__((ext_vector_type(16)));
typedef float f32x4  __attribute__((ext_vector_type(4)));

// ---- workspace layout (bytes) ----
// [0,4096)        barrier counters: one uint per row-group, stride 256
// [4096,528384)   h ping-pong: parity p at 4096+p*262144, each {hi,lo}[128][512] bf16
// [528384,790528) h_T f32 [128][512]
// [1MiB,9MiB)     packed W fragments: 64 slices x 128KiB
static const size_t WS_HBUF  = 4096;
static const size_t WS_HT    = 4096 + 524288;
static const size_t WS_WPACK = (size_t)1 << 20;

__device__ __forceinline__ unsigned short f2bf(float f) {
  unsigned u = __float_as_uint(f);
  unsigned r = u + 0x7FFFu + ((u >> 16) & 1u);   // RNE, inputs finite
  return (unsigned short)(r >> 16);
}
__device__ __forceinline__ float bf2f(unsigned short b) {
  return __uint_as_float(((unsigned)b) << 16);
}
__device__ __forceinline__ float sigm(float z) {
  z = fminf(30.f, fmaxf(-30.f, z));
  return 1.f / (1.f + __expf(-z));
}
__device__ __forceinline__ float tanh_(float z) {
  float az = fminf(fabsf(z), 40.f);
  float e = __expf(-2.f * az);                   // e <= 1, no overflow
  float t = (1.f - e) / (1.f + e);
  return z < 0.f ? -t : t;
}

// Pack [W_hh | W_ih] (K=1024 stacked) into per-slice MFMA B-fragment order:
// wp[p][s][split][kg][col][8] bf16, p=col-slice 0..63, s=K/16 slice 0..63,
// split 0=hi 1=lo, kg=lane>>5, col=lane&31 (col = gate*8 + unit_within_slice).
__global__ void __launch_bounds__(256, 1)
pack_w(const float* __restrict__ Wih, const float* __restrict__ Whh,
       unsigned short* __restrict__ wp) {
  int cid = blockIdx.x * 256 + threadIdx.x;      // 0..524287, one 16B chunk each
  int col   = cid & 31;
  int kg    = (cid >> 5) & 1;
  int split = (cid >> 6) & 1;
  int s     = (cid >> 7) & 63;
  int p     = cid >> 13;
  int k     = s * 16 + kg * 8;
  int gcol  = (col >> 3) * 512 + p * 8 + (col & 7);
  const float* src = (k < 512) ? (Whh + (size_t)gcol * 512 + k)
                               : (Wih + (size_t)gcol * 512 + (k - 512));
  bf16x8 o;
  #pragma unroll
  for (int i = 0; i < 8; i++) {
    float v = src[i];
    unsigned short h = f2bf(v);
    o[i] = (short)((split == 0) ? h : f2bf(v - bf2f(h)));
  }
  *(bf16x8*)(wp + (size_t)cid * 8) = o;
}

__global__ void __launch_bounds__(256, 1)
urlstm_rec(const float* __restrict__ xs, const float* __restrict__ bias,
           const float* __restrict__ fbias, unsigned char* __restrict__ ws) {
  extern __shared__ char smem[];
  unsigned short* Wlds = (unsigned short*)smem;   // 128 KiB: resident B slice
  float* red = (float*)(smem + 131072);           // 16 KiB: K-partial reduction

  const int tid  = threadIdx.x;
  const int wave = tid >> 6;        // K-quarter owner
  const int lane = tid & 63;
  const int lrow = lane & 31;
  const int half = lane >> 5;
  const int g = blockIdx.x >> 6;    // row group 0..3 (32 batch rows each)
  const int p = blockIdx.x & 63;    // col slice 0..63 (8 hidden units each)

  unsigned int* cnt = (unsigned int*)(ws + (size_t)g * 256);
  const unsigned short* wpg = (const unsigned short*)(ws + WS_WPACK) + (size_t)p * 65536;

  { // stage W slice into LDS (linear 128 KiB copy)
    const float4* srcv = (const float4*)wpg;
    float4* dstv = (float4*)Wlds;
    for (int i = tid; i < 8192; i += 256) dstv[i] = srcv[i];
  }

  const int col = lane & 31;        // MFMA C col = gate*8 + j
  const int j   = lane & 7;
  const int jg  = p * 8 + j;        // global hidden unit
  const float biasv = bias[(col >> 3) * 512 + p * 8 + (col & 7)];
  const float fbv   = fbias[jg];

  unsigned short* hbuf = (unsigned short*)(ws + WS_HBUF);
  float* hT = (float*)(ws + WS_HT);

  const int grow0 = g * 32;
  const int arow  = grow0 + lrow;   // A-fragment batch row

  float c_st[4] = {0.f, 0.f, 0.f, 0.f};
  bool dead = false;

  __syncthreads();                  // Wlds ready

  #pragma unroll 1
  for (int t = 0; t < NT; t++) {
    const unsigned short* h_hi = hbuf + (size_t)(t & 1) * 131072;
    const unsigned short* h_lo = h_hi + 65536;

    f32x16 acc = {};
    #pragma unroll 4
    for (int kk = 0; kk < 16; kk++) {
      const int s = wave * 16 + kk;            // global K/16 slice
      bf16x8 Ah, Al;
      if (wave < 2) {                          // h part of A (k<512)
        const int k = s * 16 + half * 8;
        Ah = *(const bf16x8*)(h_hi + (size_t)arow * 512 + k);
        Al = *(const bf16x8*)(h_lo + (size_t)arow * 512 + k);
      } else {                                 // x part (k>=512), split on the fly
        const int i0 = s * 16 + half * 8 - 512;
        const float* xp = xs + ((size_t)arow * NT + t) * NI + i0;
        float4 x0 = *(const float4*)xp;
        float4 x1 = *(const float4*)(xp + 4);
        float xv[8] = {x0.x, x0.y, x0.z, x0.w, x1.x, x1.y, x1.z, x1.w};
        #pragma unroll
        for (int e = 0; e < 8; e++) {
          unsigned short hb = f2bf(xv[e]);
          Ah[e] = (short)hb;
          Al[e] = (short)f2bf(xv[e] - bf2f(hb));
        }
      }
      const unsigned short* bp = Wlds + (size_t)(s * 2) * 512 + lane * 8;
      bf16x8 Bh = *(const bf16x8*)bp;
      bf16x8 Bl = *(const bf16x8*)(bp + 512);
      acc = __builtin_amdgcn_mfma_f32_32x32x16_bf16(Ah, Bh, acc, 0, 0, 0);
      acc = __builtin_amdgcn_mfma_f32_32x32x16_bf16(Ah, Bl, acc, 0, 0, 0);
      acc = __builtin_amdgcn_mfma_f32_32x32x16_bf16(Al, Bh, acc, 0, 0, 0);
    }

    // stash this wave's K-quarter partial of the 32x32 gate tile
    float* rw = red + ((size_t)wave * 64 + lane) * 16;
    #pragma unroll
    for (int rr = 0; rr < 4; rr++) {
      f32x4 v = {acc[4*rr], acc[4*rr+1], acc[4*rr+2], acc[4*rr+3]};
      *(f32x4*)(rw + 4 * rr) = v;
    }
    __syncthreads();

    // wave w reduces regs [4w,4w+4) across the 4 K-partials, then pointwise
    const int r0 = wave * 4;
    f32x4 sum = {};
    #pragma unroll
    for (int pw = 0; pw < 4; pw++)
      sum += *(const f32x4*)(red + ((size_t)pw * 64 + lane) * 16 + r0);

    unsigned short* ho_hi = hbuf + (size_t)((t + 1) & 1) * 131072;
    unsigned short* ho_lo = ho_hi + 65536;
    const bool writer = (col < 8);             // gate-0 lanes own the writeback
    const int srcbase = (lane & 32) | j;

    #pragma unroll
    for (int q = 0; q < 4; q++) {
      float a = sum[q] + biasv;                // biased gate pre-activation (my col)
      float fv = __shfl(a, srcbase);           // forget  (col j)
      float rv = __shfl(a, srcbase + 8);       // refine  (col 8+j)
      float uv = __shfl(a, srcbase + 16);      // cand    (col 16+j)
      float ov = __shfl(a, srcbase + 24);      // output  (col 24+j)
      float fg = sigm(fv + fbv);
      float rg = sigm(rv - fbv);
      float gg = 2.f * rg * fg + (1.f - 2.f * rg) * fg * fg;
      float cn = gg * c_st[q] + (1.f - gg) * tanh_(uv);
      float hn = sigm(ov) * tanh_(cn);
      c_st[q] = cn;
      if (writer) {
        int row = grow0 + q + 8 * wave + 4 * half;   // C-layout row
        unsigned short hb = f2bf(hn);
        ho_hi[(size_t)row * 512 + jg] = hb;
        ho_lo[(size_t)row * 512 + jg] = f2bf(hn - bf2f(hb));
        if (t == NT - 1) hT[(size_t)row * 512 + jg] = hn;
      }
    }

    if (t != NT - 1) {
      __syncthreads();                         // all h stores drained (vmcnt 0)
      if (tid == 0 && !dead) {
        __threadfence();                       // L2 writeback (cross-XCD release)
        __hip_atomic_fetch_add(cnt, 1u, __ATOMIC_RELEASE, __HIP_MEMORY_SCOPE_AGENT);
        const unsigned target = 64u * (unsigned)(t + 1);
        int guard = 0;
        while (__hip_atomic_load(cnt, __ATOMIC_ACQUIRE, __HIP_MEMORY_SCOPE_AGENT) < target) {
          __builtin_amdgcn_s_sleep(1);
          if (++guard > (1 << 21)) { dead = true; break; }  // fail loud, not hung
        }
      }
      __syncthreads();
    }
  }
}

__global__ void __launch_bounds__(256, 1)
out_proj(const unsigned char* __restrict__ ws, const float* __restrict__ Wout,
         const float* __restrict__ bout, float* __restrict__ out) {
  __shared__ float hrow[512];
  const float* hT = (const float*)(ws + WS_HT);
  const int b = blockIdx.x;
  const int o = threadIdx.x;
  for (int i = o; i < 512; i += 256) hrow[i] = hT[(size_t)b * 512 + i];
  __syncthreads();
  float acc = bout[o];
  const float4* w = (const float4*)(Wout + (size_t)o * 512);
  #pragma unroll 8
  for (int i = 0; i < 128; i++) {
    float4 wv = w[i];
    acc += hrow[4*i] * wv.x + hrow[4*i+1] * wv.y + hrow[4*i+2] * wv.z + hrow[4*i+3] * wv.w;
  }
  out[(size_t)b * 256 + o] = acc;
}

extern "C" void kernel_launch(void* const* d_in, const int* in_sizes, int n_in,
                              void* d_out, int out_size, void* d_ws, size_t ws_size,
                              hipStream_t stream) {
  const float* xs   = (const float*)d_in[0];
  const float* Wih  = (const float*)d_in[1];
  const float* Whh  = (const float*)d_in[2];
  const float* bias = (const float*)d_in[3];
  const float* fb   = (const float*)d_in[4];
  const float* Wout = (const float*)d_in[5];
  const float* bout = (const float*)d_in[6];
  unsigned char* ws = (unsigned char*)d_ws;

  // zero barrier counters + h parity-0 buffer (h0 = 0)
  hipMemsetAsync(ws, 0, WS_HBUF + 262144, stream);
  pack_w<<<2048, 256, 0, stream>>>(Wih, Whh, (unsigned short*)(ws + WS_WPACK));
  urlstm_rec<<<256, 256, 147456, stream>>>(xs, bias, fb, ws);
  out_proj<<<128, 256, 0, stream>>>(ws, Wout, bout, (float*)d_out);
}

// Round 2
// 5180.361 us; speedup vs baseline: 2.1394x; 2.1394x over previous
//
#include <hip/hip_runtime.h>
#include <stdint.h>

// UR-LSTM: B=128, T=512, I=512, H=512, OUT=256, 4H=2048
// Persistent 256-WG kernel; 4 row-groups x 64 col-slices.
// Per step: gates = [h|x_t](bf16 hi/lo split) @ [W_hh|W_ih]^T via 3-pass
// mfma_f32_32x32x16_bf16. Cross-WG h exchange uses RELAXED agent-scope
// atomics (sc0/sc1 coherent, NO buffer_inv/wbl2 cache maintenance).
// Waves 2,3 overlap the x-part GEMM with the barrier wait.

#define NB 128
#define NT 512
#define NI 512
#define NH 512
#define NO 256

typedef short bf16x8 __attribute__((ext_vector_type(8)));
typedef float f32x16 __attribute__((ext_vector_type(16)));
typedef float f32x4  __attribute__((ext_vector_type(4)));

// ---- workspace layout (bytes) ----
// [0,4096)        barrier counters: one uint per row-group, stride 256
// [4096,528384)   h ping-pong: parity q at 4096+q*262144, each [512 unit][128 row] u32 (bf16 hi | lo<<16)
// [1MiB,9MiB)     packed W fragments: 64 slices x 128KiB
static const size_t WS_HBUF  = 4096;
static const size_t WS_WPACK = (size_t)1 << 20;

__device__ __forceinline__ unsigned short f2bf(float f) {
  unsigned u = __float_as_uint(f);
  unsigned r = u + 0x7FFFu + ((u >> 16) & 1u);   // RNE, inputs finite
  return (unsigned short)(r >> 16);
}
__device__ __forceinline__ float bf2f(unsigned short b) {
  return __uint_as_float(((unsigned)b) << 16);
}
__device__ __forceinline__ float sigm(float z) {
  z = fminf(30.f, fmaxf(-30.f, z));
  return 1.f / (1.f + __expf(-z));
}
__device__ __forceinline__ float tanh_(float z) {
  float az = fminf(fabsf(z), 40.f);
  float e = __expf(-2.f * az);                   // e <= 1, no overflow
  float t = (1.f - e) / (1.f + e);
  return z < 0.f ? -t : t;
}

// Pack [W_hh | W_ih] (K=1024 stacked) into per-slice MFMA B-fragment order:
// wp[p][s][split][kg][col][8] bf16, p=col-slice 0..63, s=K/16 slice 0..63,
// split 0=hi 1=lo, kg=lane>>5, col=lane&31 (col = gate*8 + unit_within_slice).
__global__ void __launch_bounds__(256, 1)
pack_w(const float* __restrict__ Wih, const float* __restrict__ Whh,
       unsigned short* __restrict__ wp) {
  int cid = blockIdx.x * 256 + threadIdx.x;      // 0..524287, one 16B chunk each
  int col   = cid & 31;
  int kg    = (cid >> 5) & 1;
  int split = (cid >> 6) & 1;
  int s     = (cid >> 7) & 63;
  int p     = cid >> 13;
  int k     = s * 16 + kg * 8;
  int gcol  = (col >> 3) * 512 + p * 8 + (col & 7);
  const float* src = (k < 512) ? (Whh + (size_t)gcol * 512 + k)
                               : (Wih + (size_t)gcol * 512 + (k - 512));
  bf16x8 o;
  #pragma unroll
  for (int i = 0; i < 8; i++) {
    float v = src[i];
    unsigned short h = f2bf(v);
    o[i] = (short)((split == 0) ? h : f2bf(v - bf2f(h)));
  }
  *(bf16x8*)(wp + (size_t)cid * 8) = o;
}

__global__ void __launch_bounds__(256, 1)
urlstm_rec(const float* __restrict__ xs, const float* __restrict__ bias,
           const float* __restrict__ fbias, unsigned char* __restrict__ ws) {
  extern __shared__ char smem[];
  unsigned short* Wlds = (unsigned short*)smem;   // 128 KiB: resident B slice
  float* red = (float*)(smem + 131072);           // 24 KiB: [6 stripe][16 reg][64 lane]

  const int tid  = threadIdx.x;
  const int wave = tid >> 6;
  const int lane = tid & 63;
  const int lrow = lane & 31;
  const int half = lane >> 5;
  const int g = blockIdx.x >> 6;    // row group 0..3 (32 batch rows each)
  const int p = blockIdx.x & 63;    // col slice 0..63 (8 hidden units each)

  unsigned int* cnt = (unsigned int*)(ws + (size_t)g * 256);
  const unsigned short* wpg = (const unsigned short*)(ws + WS_WPACK) + (size_t)p * 65536;

  { // stage W slice into LDS (linear 128 KiB copy)
    const float4* srcv = (const float4*)wpg;
    float4* dstv = (float4*)Wlds;
    for (int i = tid; i < 8192; i += 256) dstv[i] = srcv[i];
  }

  const int col = lane & 31;        // MFMA C col = gate*8 + j
  const int j   = lane & 7;
  const int jg  = p * 8 + j;        // global hidden unit
  const float biasv = bias[(col >> 3) * 512 + p * 8 + (col & 7)];
  const float fbv   = fbias[jg];

  unsigned int* hbuf = (unsigned int*)(ws + WS_HBUF);
  const int grow0 = g * 32;
  const int arow  = grow0 + lrow;   // A-fragment batch row

  float c_st[4] = {0.f, 0.f, 0.f, 0.f};

  __syncthreads();                  // Wlds ready

  #pragma unroll 1
  for (int t = 0; t < NT; t++) {
    // ---- phase A: x-part GEMM (waves 2,3) overlapped with barrier poll ----
    f32x16 accx = {};
    if (wave >= 2) {
      #pragma unroll 4
      for (int kk = 0; kk < 16; kk++) {
        const int s = 32 + (wave - 2) * 16 + kk;       // K slices 512..1023
        const int i0 = s * 16 + half * 8 - 512;
        const float* xp = xs + ((size_t)arow * NT + t) * NI + i0;
        float4 x0 = *(const float4*)xp;
        float4 x1 = *(const float4*)(xp + 4);
        float xv[8] = {x0.x, x0.y, x0.z, x0.w, x1.x, x1.y, x1.z, x1.w};
        bf16x8 Ah, Al;
        #pragma unroll
        for (int e = 0; e < 8; e++) {
          unsigned short hb = f2bf(xv[e]);
          Ah[e] = (short)hb;
          Al[e] = (short)f2bf(xv[e] - bf2f(hb));
        }
        const unsigned short* bp = Wlds + (size_t)(s * 2) * 512 + lane * 8;
        bf16x8 Bh = *(const bf16x8*)bp;
        bf16x8 Bl = *(const bf16x8*)(bp + 512);
        accx = __builtin_amdgcn_mfma_f32_32x32x16_bf16(Ah, Bh, accx, 0, 0, 0);
        accx = __builtin_amdgcn_mfma_f32_32x32x16_bf16(Ah, Bl, accx, 0, 0, 0);
        accx = __builtin_amdgcn_mfma_f32_32x32x16_bf16(Al, Bh, accx, 0, 0, 0);
      }
    } else if (tid == 0 && t > 0) {
      const unsigned target = 64u * (unsigned)t;       // all WGs finished step t-1
      unsigned int* cv = cnt;
      int guard = 0;
      while (__hip_atomic_load(cv, __ATOMIC_RELAXED, __HIP_MEMORY_SCOPE_AGENT) < target) {
        if (++guard > (1 << 22)) break;                // fail loud, not hung
      }
    }
    __syncthreads();                                   // h(t) visible to all

    // ---- phase B: h-part GEMM, all 4 waves, K=128 each ----
    f32x16 acch = {};
    if (t > 0) {
      const unsigned int* hin = hbuf + (size_t)(t & 1) * 65536;
      unsigned int hv[64];
      #pragma unroll
      for (int kk = 0; kk < 8; kk++) {
        const int k = wave * 128 + kk * 16 + half * 8;
        #pragma unroll
        for (int e = 0; e < 8; e++)
          hv[kk * 8 + e] = __hip_atomic_load(
              (unsigned int*)(hin + (size_t)(k + e) * 128 + arow),
              __ATOMIC_RELAXED, __HIP_MEMORY_SCOPE_AGENT);
      }
      #pragma unroll
      for (int kk = 0; kk < 8; kk++) {
        bf16x8 Ah, Al;
        #pragma unroll
        for (int e = 0; e < 8; e++) {
          unsigned int w = hv[kk * 8 + e];
          Ah[e] = (short)(w & 0xffffu);
          Al[e] = (short)(w >> 16);
        }
        const int s = wave * 8 + kk;                   // K slices 0..31 (h region)
        const unsigned short* bp = Wlds + (size_t)(s * 2) * 512 + lane * 8;
        bf16x8 Bh = *(const bf16x8*)bp;
        bf16x8 Bl = *(const bf16x8*)(bp + 512);
        acch = __builtin_amdgcn_mfma_f32_32x32x16_bf16(Ah, Bh, acch, 0, 0, 0);
        acch = __builtin_amdgcn_mfma_f32_32x32x16_bf16(Ah, Bl, acch, 0, 0, 0);
        acch = __builtin_amdgcn_mfma_f32_32x32x16_bf16(Al, Bh, acch, 0, 0, 0);
      }
    }

    // ---- K-partial reduction: red[stripe][reg][lane], 4B lane stride ----
    {
      float* rh = red + (size_t)wave * 1024;
      #pragma unroll
      for (int r = 0; r < 16; r++) rh[r * 64 + lane] = acch[r];
      if (wave >= 2) {
        float* rx = red + (size_t)(2 + wave) * 1024;
        #pragma unroll
        for (int r = 0; r < 16; r++) rx[r * 64 + lane] = accx[r];
      }
    }
    __syncthreads();

    const int r0 = wave * 4;
    f32x4 sum = {};
    #pragma unroll
    for (int st = 0; st < 6; st++) {
      #pragma unroll
      for (int q = 0; q < 4; q++)
        sum[q] += red[(size_t)st * 1024 + (r0 + q) * 64 + lane];
    }

    // ---- pointwise UR-LSTM update + coherent h store ----
    unsigned int* hout = hbuf + (size_t)((t + 1) & 1) * 65536;
    const bool writer = (col < 8);             // gate-0 lanes own the writeback
    const int srcbase = (lane & 32) | j;

    #pragma unroll
    for (int q = 0; q < 4; q++) {
      float a = sum[q] + biasv;                // biased gate pre-activation (my col)
      float fv = __shfl(a, srcbase);           // forget  (col j)
      float rv = __shfl(a, srcbase + 8);       // refine  (col 8+j)
      float uv = __shfl(a, srcbase + 16);      // cand    (col 16+j)
      float ov = __shfl(a, srcbase + 24);      // output  (col 24+j)
      float fg = sigm(fv + fbv);
      float rg = sigm(rv - fbv);
      float gg = 2.f * rg * fg + (1.f - 2.f * rg) * fg * fg;
      float cn = gg * c_st[q] + (1.f - gg) * tanh_(uv);
      float hn = sigm(ov) * tanh_(cn);
      c_st[q] = cn;
      if (writer) {
        int row = grow0 + q + 8 * wave + 4 * half;     // C-layout row
        unsigned short hb = f2bf(hn);
        unsigned int pw = (unsigned)hb | ((unsigned)f2bf(hn - bf2f(hb)) << 16);
        __hip_atomic_store(hout + (size_t)jg * 128 + row, pw,
                           __ATOMIC_RELAXED, __HIP_MEMORY_SCOPE_AGENT);
      }
    }

    if (t != NT - 1) {
      asm volatile("s_waitcnt vmcnt(0)" ::: "memory");  // coherent stores done
      __syncthreads();                                  // whole WG's stores done
      if (tid == 0)
        __hip_atomic_fetch_add(cnt, 1u, __ATOMIC_RELAXED, __HIP_MEMORY_SCOPE_AGENT);
    }
  }
}

__global__ void __launch_bounds__(256, 1)
out_proj(const unsigned char* __restrict__ ws, const float* __restrict__ Wout,
         const float* __restrict__ bout, float* __restrict__ out) {
  __shared__ float hrow[512];
  const unsigned int* hT = (const unsigned int*)(ws + WS_HBUF);  // parity 0 = h(512)
  const int b = blockIdx.x;
  const int o = threadIdx.x;
  for (int i = o; i < 512; i += 256) {
    unsigned int w = hT[(size_t)i * 128 + b];
    hrow[i] = bf2f((unsigned short)(w & 0xffffu)) + bf2f((unsigned short)(w >> 16));
  }
  __syncthreads();
  float acc = bout[o];
  const float4* w = (const float4*)(Wout + (size_t)o * 512);
  #pragma unroll 8
  for (int i = 0; i < 128; i++) {
    float4 wv = w[i];
    acc += hrow[4*i] * wv.x + hrow[4*i+1] * wv.y + hrow[4*i+2] * wv.z + hrow[4*i+3] * wv.w;
  }
  out[(size_t)b * 256 + o] = acc;
}

extern "C" void kernel_launch(void* const* d_in, const int* in_sizes, int n_in,
                              void* d_out, int out_size, void* d_ws, size_t ws_size,
                              hipStream_t stream) {
  const float* xs   = (const float*)d_in[0];
  const float* Wih  = (const float*)d_in[1];
  const float* Whh  = (const float*)d_in[2];
  const float* bias = (const float*)d_in[3];
  const float* fb   = (const float*)d_in[4];
  const float* Wout = (const float*)d_in[5];
  const float* bout = (const float*)d_in[6];
  unsigned char* ws = (unsigned char*)d_ws;

  hipMemsetAsync(ws, 0, 4096, stream);  // barrier counters only (t=0 skips h)
  pack_w<<<2048, 256, 0, stream>>>(Wih, Whh, (unsigned short*)(ws + WS_WPACK));
  urlstm_rec<<<256, 256, 155648, stream>>>(xs, bias, fb, ws);
  out_proj<<<128, 256, 0, stream>>>(ws, Wout, bout, (float*)d_out);
}